// Round 1
// baseline (639.109 us; speedup 1.0000x reference)
//
#include <hip/hip_runtime.h>
#include <math.h>

#define B_DIM 2048
#define D_DIM 256
#define H1 512
#define H2 256
#define LBL 10
#define M_ROWS (B_DIM * LBL)

__device__ __forceinline__ void acc4(float4& s, const float4 a) {
  s.x += a.x; s.y += a.y; s.z += a.z; s.w += a.w;
}

__device__ __forceinline__ float leaky(float v) { return v > 0.f ? v : 0.01f * v; }

// ---------------- Kernel A: prefix means -> h [B][LBL][D] ----------------
// One wave per batch; lane owns 4 channels (float4). Running sum over t,
// emit h rows for t in [L-10, L-1].
__global__ __launch_bounds__(256) void prefix_kernel(
    const float* __restrict__ x, const int* __restrict__ lens,
    float* __restrict__ h) {
  const int wv = threadIdx.x >> 6;
  const int lane = threadIdx.x & 63;
  const int b = blockIdx.x * 4 + wv;
  const int L = lens[b];
  const int Lm = L - LBL;
  const size_t ts = (size_t)(B_DIM * D_DIM / 4);  // float4 stride per t
  const float4* xb = reinterpret_cast<const float4*>(x) + (size_t)b * (D_DIM / 4) + lane;
  float4 s0 = make_float4(0.f, 0.f, 0.f, 0.f), s1 = s0, s2 = s0, s3 = s0;
  int t = 0;
  for (; t + 8 <= Lm; t += 8) {
    float4 a0 = xb[(size_t)(t + 0) * ts], a1 = xb[(size_t)(t + 1) * ts];
    float4 a2 = xb[(size_t)(t + 2) * ts], a3 = xb[(size_t)(t + 3) * ts];
    float4 a4 = xb[(size_t)(t + 4) * ts], a5 = xb[(size_t)(t + 5) * ts];
    float4 a6 = xb[(size_t)(t + 6) * ts], a7 = xb[(size_t)(t + 7) * ts];
    acc4(s0, a0); acc4(s1, a1); acc4(s2, a2); acc4(s3, a3);
    acc4(s0, a4); acc4(s1, a5); acc4(s2, a6); acc4(s3, a7);
  }
  for (; t < Lm; ++t) acc4(s0, xb[(size_t)t * ts]);
  acc4(s0, s1); acc4(s2, s3); acc4(s0, s2);
  float4* hout = reinterpret_cast<float4*>(h) + (size_t)b * (LBL * D_DIM / 4) + lane;
  #pragma unroll
  for (int k = 0; k < LBL; ++k) {
    const int tt = Lm + k;
    acc4(s0, xb[(size_t)tt * ts]);
    const float inv = 1.0f / (float)(tt + 1);
    float4 o;
    o.x = s0.x * inv; o.y = s0.y * inv; o.z = s0.z * inv; o.w = s0.w * inv;
    hout[(size_t)k * (D_DIM / 4)] = o;
  }
}

// ---------------- Kernel B: fused two-tower MLP over 32-row tiles ----------
// block = 256 threads; thread (rt = tid&7, nt = tid>>3) computes a
// 4-row x 16-col (layer1) / 4x8 (layer2) register tile.
__global__ __launch_bounds__(256) void tower_kernel(
    const float* __restrict__ h,
    const float* __restrict__ W1a, const float* __restrict__ b1a,
    const float* __restrict__ W2a, const float* __restrict__ b2a,
    const float* __restrict__ W3a, const float* __restrict__ b3a,
    const float* __restrict__ W1b, const float* __restrict__ b1b,
    const float* __restrict__ W2b, const float* __restrict__ b2b,
    const float* __restrict__ W3b, const float* __restrict__ b3b,
    float* __restrict__ out) {
  __shared__ float hs[32][D_DIM + 1];   // +1 pad: rt-groups land on distinct banks
  __shared__ float A1[32][H1 + 1];
  __shared__ float Zs[32][H2 + 1];
  const int tid = threadIdx.x;
  const int r0 = blockIdx.x * 32;

  {  // stage 32 h rows (32 KB) into LDS, coalesced float4
    const float4* hp = reinterpret_cast<const float4*>(h + (size_t)r0 * D_DIM);
    #pragma unroll
    for (int i = 0; i < 8; ++i) {
      const int idx = tid + i * 256;
      const int rr = idx >> 6, cc = idx & 63;
      const float4 v = hp[(size_t)rr * 64 + cc];
      hs[rr][cc * 4 + 0] = v.x; hs[rr][cc * 4 + 1] = v.y;
      hs[rr][cc * 4 + 2] = v.z; hs[rr][cc * 4 + 3] = v.w;
    }
  }
  __syncthreads();

  const int rt = tid & 7;   // row group: rows rt*4 .. rt*4+3
  const int nt = tid >> 3;  // col group 0..31
  const int row = nt;       // layer-3 mapping
  const int jj = rt;
  float sig[2];

  for (int tw = 0; tw < 2; ++tw) {
    const float* __restrict__ W1 = tw ? W1b : W1a;
    const float* __restrict__ B1 = tw ? b1b : b1a;
    const float* __restrict__ W2 = tw ? W2b : W2a;
    const float* __restrict__ B2 = tw ? b2b : b2a;
    const float* __restrict__ W3 = tw ? W3b : W3a;
    const float* __restrict__ B3 = tw ? b3b : b3a;

    // ---- layer 1: hs[32x256] @ W1[256x512] -> A1[32x512], leaky
    float acc[4][16];
    #pragma unroll
    for (int i = 0; i < 4; ++i)
      #pragma unroll
      for (int c = 0; c < 16; ++c) acc[i][c] = B1[nt * 16 + c];
    #pragma unroll 2
    for (int k = 0; k < D_DIM; ++k) {
      const float4* wr = reinterpret_cast<const float4*>(W1 + (size_t)k * H1 + nt * 16);
      const float4 w0 = wr[0], w1 = wr[1], w2 = wr[2], w3 = wr[3];
      float hv[4];
      #pragma unroll
      for (int i = 0; i < 4; ++i) hv[i] = hs[rt * 4 + i][k];
      const float wv[16] = {w0.x, w0.y, w0.z, w0.w, w1.x, w1.y, w1.z, w1.w,
                            w2.x, w2.y, w2.z, w2.w, w3.x, w3.y, w3.z, w3.w};
      #pragma unroll
      for (int i = 0; i < 4; ++i)
        #pragma unroll
        for (int c = 0; c < 16; ++c)
          acc[i][c] = fmaf(hv[i], wv[c], acc[i][c]);
    }
    #pragma unroll
    for (int i = 0; i < 4; ++i)
      #pragma unroll
      for (int c = 0; c < 16; ++c)
        A1[rt * 4 + i][nt * 16 + c] = leaky(acc[i][c]);
    __syncthreads();

    // ---- layer 2: A1[32x512] @ W2[512x256] -> Zs[32x256], leaky
    float acc2[4][8];
    #pragma unroll
    for (int i = 0; i < 4; ++i)
      #pragma unroll
      for (int c = 0; c < 8; ++c) acc2[i][c] = B2[nt * 8 + c];
    #pragma unroll 2
    for (int k = 0; k < H1; ++k) {
      const float4* wr = reinterpret_cast<const float4*>(W2 + (size_t)k * H2 + nt * 8);
      const float4 w0 = wr[0], w1 = wr[1];
      float av[4];
      #pragma unroll
      for (int i = 0; i < 4; ++i) av[i] = A1[rt * 4 + i][k];
      const float wv[8] = {w0.x, w0.y, w0.z, w0.w, w1.x, w1.y, w1.z, w1.w};
      #pragma unroll
      for (int i = 0; i < 4; ++i)
        #pragma unroll
        for (int c = 0; c < 8; ++c)
          acc2[i][c] = fmaf(av[i], wv[c], acc2[i][c]);
    }
    #pragma unroll
    for (int i = 0; i < 4; ++i)
      #pragma unroll
      for (int c = 0; c < 8; ++c)
        Zs[rt * 4 + i][nt * 8 + c] = leaky(acc2[i][c]);
    __syncthreads();

    // ---- layer 3: Zs[32x256] @ w3[256] -> z, leaky, sigmoid
    float p = 0.f;
    #pragma unroll
    for (int m = 0; m < 32; ++m)
      p = fmaf(Zs[row][jj * 32 + m], W3[jj * 32 + m], p);
    p += __shfl_xor(p, 1);
    p += __shfl_xor(p, 2);
    p += __shfl_xor(p, 4);
    const float z = leaky(p + B3[0]);
    sig[tw] = 1.f / (1.f + expf(-z));
    __syncthreads();  // A1/Zs reused by next tower
  }
  if (jj == 0) out[r0 + row] = sig[0] * sig[1];
}

extern "C" void kernel_launch(void* const* d_in, const int* in_sizes, int n_in,
                              void* d_out, int out_size, void* d_ws, size_t ws_size,
                              hipStream_t stream) {
  (void)in_sizes; (void)n_in; (void)out_size; (void)ws_size;
  const float* x    = (const float*)d_in[0];
  const int*   lens = (const int*)d_in[1];
  // d_in[2] = label_len (hard-coded 10)
  const float* cW1 = (const float*)d_in[3];
  const float* cb1 = (const float*)d_in[4];
  const float* cW2 = (const float*)d_in[5];
  const float* cb2 = (const float*)d_in[6];
  const float* cW3 = (const float*)d_in[7];
  const float* cb3 = (const float*)d_in[8];
  const float* vW1 = (const float*)d_in[9];
  const float* vb1 = (const float*)d_in[10];
  const float* vW2 = (const float*)d_in[11];
  const float* vb2 = (const float*)d_in[12];
  const float* vW3 = (const float*)d_in[13];
  const float* vb3 = (const float*)d_in[14];
  float* out  = (float*)d_out;
  float* hbuf = (float*)d_ws;  // [M_ROWS][D_DIM] f32 = 20 MB

  prefix_kernel<<<B_DIM / 4, 256, 0, stream>>>(x, lens, hbuf);
  tower_kernel<<<M_ROWS / 32, 256, 0, stream>>>(
      hbuf, cW1, cb1, cW2, cb2, cW3, cb3, vW1, vb1, vW2, vb2, vW3, vb3, out);
}

// Round 3
// 513.962 us; speedup vs baseline: 1.2435x; 1.2435x over previous
//
#include <hip/hip_runtime.h>
#include <math.h>

#define B_DIM 2048
#define D_DIM 256
#define H1 512
#define H2 256
#define LBL 10
#define M_ROWS (B_DIM * LBL)
#define HCH 256      // H1 half-chunk (layer1/layer2 fused per half)
#define A1_LD 260    // padded leading dim: 16B-aligned, spreads row-pairs across banks

__device__ __forceinline__ void acc4(float4& s, const float4 a) {
  s.x += a.x; s.y += a.y; s.z += a.z; s.w += a.w;
}

__device__ __forceinline__ float leaky(float v) { return v > 0.f ? v : 0.01f * v; }

// ---------------- Kernel A: prefix means -> h [B][LBL][D] ----------------
__global__ __launch_bounds__(256) void prefix_kernel(
    const float* __restrict__ x, const int* __restrict__ lens,
    float* __restrict__ h) {
  const int wv = threadIdx.x >> 6;
  const int lane = threadIdx.x & 63;
  const int b = blockIdx.x * 4 + wv;
  const int L = lens[b];
  const int Lm = L - LBL;
  const size_t ts = (size_t)(B_DIM * D_DIM / 4);
  const float4* xb = reinterpret_cast<const float4*>(x) + (size_t)b * (D_DIM / 4) + lane;
  float4 s0 = make_float4(0.f, 0.f, 0.f, 0.f), s1 = s0, s2 = s0, s3 = s0;
  int t = 0;
  for (; t + 8 <= Lm; t += 8) {
    float4 a0 = xb[(size_t)(t + 0) * ts], a1 = xb[(size_t)(t + 1) * ts];
    float4 a2 = xb[(size_t)(t + 2) * ts], a3 = xb[(size_t)(t + 3) * ts];
    float4 a4 = xb[(size_t)(t + 4) * ts], a5 = xb[(size_t)(t + 5) * ts];
    float4 a6 = xb[(size_t)(t + 6) * ts], a7 = xb[(size_t)(t + 7) * ts];
    acc4(s0, a0); acc4(s1, a1); acc4(s2, a2); acc4(s3, a3);
    acc4(s0, a4); acc4(s1, a5); acc4(s2, a6); acc4(s3, a7);
  }
  for (; t < Lm; ++t) acc4(s0, xb[(size_t)t * ts]);
  acc4(s0, s1); acc4(s2, s3); acc4(s0, s2);
  float4* hout = reinterpret_cast<float4*>(h) + (size_t)b * (LBL * D_DIM / 4) + lane;
  #pragma unroll
  for (int k = 0; k < LBL; ++k) {
    const int tt = Lm + k;
    acc4(s0, xb[(size_t)tt * ts]);
    const float inv = 1.0f / (float)(tt + 1);
    float4 o;
    o.x = s0.x * inv; o.y = s0.y * inv; o.z = s0.z * inv; o.w = s0.w * inv;
    hout[(size_t)k * (D_DIM / 4)] = o;
  }
}

// ---------------- Kernel B: fused two-tower MLP, 32 rows/block -------------
// 256 threads: rt = tid>>5 (rows rt*4..+3), nt = tid&31 (cols nt*8..+7).
// Layer1 computed in two 256-col halves; each half immediately accumulated
// into register-resident layer-2 outputs Z[4][8]. Only A1-half lives in LDS
// (33 KB) -> 3 blocks/CU with __launch_bounds__(256,3).
__global__ __launch_bounds__(256, 3) void tower_kernel(
    const float* __restrict__ h,
    const float* __restrict__ W1a, const float* __restrict__ b1a,
    const float* __restrict__ W2a, const float* __restrict__ b2a,
    const float* __restrict__ W3a, const float* __restrict__ b3a,
    const float* __restrict__ W1b, const float* __restrict__ b1b,
    const float* __restrict__ W2b, const float* __restrict__ b2b,
    const float* __restrict__ W3b, const float* __restrict__ b3b,
    float* __restrict__ out) {
  __shared__ float A1h[32][A1_LD];
  const int tid = threadIdx.x;
  const int rt = tid >> 5;   // row group (8): rows rt*4..rt*4+3
  const int nt = tid & 31;   // col group (32): 8 cols each
  const int r0 = blockIdx.x * 32;
  const float* __restrict__ hr0 = h + (size_t)(r0 + rt * 4) * D_DIM;

  float sigp[4];

  for (int tw = 0; tw < 2; ++tw) {
    const float* __restrict__ W1 = tw ? W1b : W1a;
    const float* __restrict__ B1 = tw ? b1b : b1a;
    const float* __restrict__ W2 = tw ? W2b : W2a;
    const float* __restrict__ B2 = tw ? b2b : b2a;
    const float* __restrict__ W3 = tw ? W3b : W3a;
    const float* __restrict__ B3 = tw ? b3b : b3a;

    float Z[4][8];
    #pragma unroll
    for (int i = 0; i < 4; ++i)
      #pragma unroll
      for (int c = 0; c < 8; ++c) Z[i][c] = B2[nt * 8 + c];

    for (int half = 0; half < 2; ++half) {
      const int c0 = half * HCH;

      // ---- layer-1 half: a[4][8] = leaky(h[rows] @ W1[:, c0+nt*8 .. +7])
      float a[4][8];
      #pragma unroll
      for (int i = 0; i < 4; ++i)
        #pragma unroll
        for (int c = 0; c < 8; ++c) a[i][c] = B1[c0 + nt * 8 + c];

      #pragma unroll 2
      for (int k = 0; k < D_DIM; k += 4) {
        float hv[4][4];
        #pragma unroll
        for (int i = 0; i < 4; ++i) {
          const float4 v = *reinterpret_cast<const float4*>(hr0 + (size_t)i * D_DIM + k);
          hv[i][0] = v.x; hv[i][1] = v.y; hv[i][2] = v.z; hv[i][3] = v.w;
        }
        #pragma unroll
        for (int kk = 0; kk < 4; ++kk) {
          const float4* wr =
              reinterpret_cast<const float4*>(W1 + (size_t)(k + kk) * H1 + c0 + nt * 8);
          const float4 w0 = wr[0], w1 = wr[1];
          const float wv[8] = {w0.x, w0.y, w0.z, w0.w, w1.x, w1.y, w1.z, w1.w};
          #pragma unroll
          for (int i = 0; i < 4; ++i)
            #pragma unroll
            for (int c = 0; c < 8; ++c)
              a[i][c] = fmaf(hv[i][kk], wv[c], a[i][c]);
        }
      }
      #pragma unroll
      for (int i = 0; i < 4; ++i) {
        float4 s0, s1;
        s0.x = leaky(a[i][0]); s0.y = leaky(a[i][1]);
        s0.z = leaky(a[i][2]); s0.w = leaky(a[i][3]);
        s1.x = leaky(a[i][4]); s1.y = leaky(a[i][5]);
        s1.z = leaky(a[i][6]); s1.w = leaky(a[i][7]);
        float* dst = &A1h[rt * 4 + i][nt * 8];
        *reinterpret_cast<float4*>(dst) = s0;
        *reinterpret_cast<float4*>(dst + 4) = s1;
      }
      __syncthreads();

      // ---- layer-2 partial: Z += A1h[rows][0:256] @ W2[c0:c0+256, nt*8..+7]
      #pragma unroll 2
      for (int k = 0; k < HCH; k += 4) {
        float av[4][4];
        #pragma unroll
        for (int i = 0; i < 4; ++i) {
          const float4 v = *reinterpret_cast<const float4*>(&A1h[rt * 4 + i][k]);
          av[i][0] = v.x; av[i][1] = v.y; av[i][2] = v.z; av[i][3] = v.w;
        }
        #pragma unroll
        for (int kk = 0; kk < 4; ++kk) {
          const float4* wr =
              reinterpret_cast<const float4*>(W2 + (size_t)(c0 + k + kk) * H2 + nt * 8);
          const float4 w0 = wr[0], w1 = wr[1];
          const float wv[8] = {w0.x, w0.y, w0.z, w0.w, w1.x, w1.y, w1.z, w1.w};
          #pragma unroll
          for (int i = 0; i < 4; ++i)
            #pragma unroll
            for (int c = 0; c < 8; ++c)
              Z[i][c] = fmaf(av[i][kk], wv[c], Z[i][c]);
        }
      }
      __syncthreads();  // A1h reused by next half / next tower
    }

    // ---- layer 3: per-row dot(leaky(Z[row]), w3) reduced over nt
    float part[4] = {0.f, 0.f, 0.f, 0.f};
    #pragma unroll
    for (int c = 0; c < 8; ++c) {
      const float w3v = W3[nt * 8 + c];
      #pragma unroll
      for (int i = 0; i < 4; ++i)
        part[i] = fmaf(leaky(Z[i][c]), w3v, part[i]);
    }
    const float bb = B3[0];
    #pragma unroll
    for (int i = 0; i < 4; ++i) {
      float p = part[i];
      p += __shfl_xor(p, 1);
      p += __shfl_xor(p, 2);
      p += __shfl_xor(p, 4);
      p += __shfl_xor(p, 8);
      p += __shfl_xor(p, 16);
      const float z = leaky(p + bb);
      const float s = 1.f / (1.f + expf(-z));
      sigp[i] = tw ? sigp[i] * s : s;
    }
  }

  if (nt == 0) {
    #pragma unroll
    for (int i = 0; i < 4; ++i) out[r0 + rt * 4 + i] = sigp[i];
  }
}

extern "C" void kernel_launch(void* const* d_in, const int* in_sizes, int n_in,
                              void* d_out, int out_size, void* d_ws, size_t ws_size,
                              hipStream_t stream) {
  (void)in_sizes; (void)n_in; (void)out_size; (void)ws_size;
  const float* x    = (const float*)d_in[0];
  const int*   lens = (const int*)d_in[1];
  // d_in[2] = label_len (hard-coded 10)
  const float* cW1 = (const float*)d_in[3];
  const float* cb1 = (const float*)d_in[4];
  const float* cW2 = (const float*)d_in[5];
  const float* cb2 = (const float*)d_in[6];
  const float* cW3 = (const float*)d_in[7];
  const float* cb3 = (const float*)d_in[8];
  const float* vW1 = (const float*)d_in[9];
  const float* vb1 = (const float*)d_in[10];
  const float* vW2 = (const float*)d_in[11];
  const float* vb2 = (const float*)d_in[12];
  const float* vW3 = (const float*)d_in[13];
  const float* vb3 = (const float*)d_in[14];
  float* out  = (float*)d_out;
  float* hbuf = (float*)d_ws;  // [M_ROWS][D_DIM] f32 = 20 MB

  prefix_kernel<<<B_DIM / 4, 256, 0, stream>>>(x, lens, hbuf);
  tower_kernel<<<M_ROWS / 32, 256, 0, stream>>>(
      hbuf, cW1, cb1, cW2, cb2, cW3, cb3, vW1, vb1, vW2, vb2, vW3, vb3, out);
}